// Round 4
// baseline (362.566 us; speedup 1.0000x reference)
//
#include <hip/hip_runtime.h>
#include <math.h>

// TopKRouter: logits = rf @ gw^T, softmax, top-2, aux load-balance loss.
// rf: [16384, 4096] f32, gw: [64, 4096] f32.
// out (f32 flat): weights [0,32768) | indices-as-float [32768,65536) | aux [65536]
//
// R3: barrier-free streaming GEMM. lane = d-slot; block = 8 rows x 64 experts;
// wave w handles experts 8w..8w+7. Both a and w stream coalesced from global
// (no LDS, no barriers in hot loop). Cross-lane butterfly reduce + fused
// epilogue. ws: [0,256) psum f32[64] | [256,512) cnt u32[64].

constexpr int B_ROWS = 16384;
constexpr int D_DIM  = 4096;
constexpr int E_EXP  = 64;
constexpr int RPB    = 8;     // rows per block
constexpr int NTHR   = 512;   // 8 waves

__device__ __forceinline__ float wave_max64(float v) {
#pragma unroll
  for (int m = 32; m >= 1; m >>= 1) v = fmaxf(v, __shfl_xor(v, m, 64));
  return v;
}

__device__ __forceinline__ float wave_sum64(float v) {
#pragma unroll
  for (int m = 32; m >= 1; m >>= 1) v += __shfl_xor(v, m, 64);
  return v;
}

// argmax over 64 lanes; ties -> smaller index (matches jax.lax.top_k)
__device__ __forceinline__ void wave_argmax64(float v, int i, float& mv, int& mi) {
#pragma unroll
  for (int m = 32; m >= 1; m >>= 1) {
    float ov = __shfl_xor(v, m, 64);
    int   oi = __shfl_xor(i, m, 64);
    if (ov > v || (ov == v && oi < i)) { v = ov; i = oi; }
  }
  mv = v; mi = i;
}

__global__ __launch_bounds__(NTHR, 2) void router_stream(
    const float* __restrict__ rf, const float* __restrict__ gw,
    float* __restrict__ out, float* __restrict__ psum,
    unsigned int* __restrict__ cnt) {
  __shared__ float lt[RPB][E_EXP + 1];   // final logits tile (+1 pad)
  __shared__ float sP[RPB][E_EXP];
  __shared__ unsigned int scnt[E_EXP];

  const int t    = threadIdx.x;
  const int wv   = t >> 6;               // wave = expert group
  const int lane = t & 63;               // lane = d-slot (4 floats)
  const int row0 = blockIdx.x * RPB;
  const int e0   = wv * 8;

  if (t < E_EXP) scnt[t] = 0;

  const float* ab = rf + (size_t)row0 * D_DIM + 4 * lane;
  const float* wb = gw + (size_t)e0 * D_DIM + 4 * lane;

  float acc[RPB][8];
#pragma unroll
  for (int i = 0; i < RPB; ++i)
#pragma unroll
    for (int j = 0; j < 8; ++j) acc[i][j] = 0.f;

  float4 aA[8], wA[8], aB[8], wB[8];

  auto LD = [&](float4* dst, const float* base, const int d) {
#pragma unroll
    for (int i = 0; i < 8; ++i)
      dst[i] = *(const float4*)(base + (size_t)i * D_DIM + d);
  };
  auto FMA = [&](const float4* a, const float4* w) {
#pragma unroll
    for (int i = 0; i < RPB; ++i)
#pragma unroll
      for (int j = 0; j < 8; ++j) {
        acc[i][j] = fmaf(a[i].x, w[j].x, acc[i][j]);
        acc[i][j] = fmaf(a[i].y, w[j].y, acc[i][j]);
        acc[i][j] = fmaf(a[i].z, w[j].z, acc[i][j]);
        acc[i][j] = fmaf(a[i].w, w[j].w, acc[i][j]);
      }
  };

  // 16 k-steps of 256 d each; 2-deep register pipeline (A/B), no barriers.
  LD(aA, ab, 0); LD(wA, wb, 0);
  for (int s = 0; s < 8; ++s) {
    const int d1 = (2 * s + 1) * 256;
    LD(aB, ab, d1); LD(wB, wb, d1);
    FMA(aA, wA);
    if (s < 7) {
      const int d2 = (2 * s + 2) * 256;
      LD(aA, ab, d2); LD(wA, wb, d2);
    }
    FMA(aB, wB);
  }

  // reduce each acc over the 64 d-slot lanes (butterfly; all lanes get sum)
#pragma unroll
  for (int i = 0; i < RPB; ++i)
#pragma unroll
    for (int j = 0; j < 8; ++j) acc[i][j] = wave_sum64(acc[i][j]);

  if (lane == 0) {
#pragma unroll
    for (int i = 0; i < RPB; ++i)
#pragma unroll
      for (int j = 0; j < 8; ++j) lt[i][e0 + j] = acc[i][j];
  }
  __syncthreads();

  // epilogue: wave wv handles row wv; lane = expert index
  {
    const int r = wv;
    const float lg = lt[r][lane];
    const float m  = wave_max64(lg);
    const float p  = __expf(lg - m);
    const float ss = wave_sum64(p);
    sP[r][lane] = p / ss;

    float v1; int i1;
    wave_argmax64(lg, lane, v1, i1);
    const float lm = (lane == i1) ? -INFINITY : lg;
    float v2; int i2;
    wave_argmax64(lm, lane, v2, i2);
    if (lane == 0) {
      const float ex = expf(v2 - v1);    // v2 <= v1, stable
      const float w1 = 1.f / (1.f + ex);
      const float w2 = ex / (1.f + ex);
      const int row = row0 + r;
      out[row * 2 + 0] = w1;
      out[row * 2 + 1] = w2;
      out[2 * B_ROWS + row * 2 + 0] = (float)i1;
      out[2 * B_ROWS + row * 2 + 1] = (float)i2;
      atomicAdd(&scnt[i1], 1u);
      atomicAdd(&scnt[i2], 1u);
    }
  }
  __syncthreads();

  if (t < E_EXP) {
    float tot = 0.f;
#pragma unroll
    for (int r = 0; r < RPB; ++r) tot += sP[r][t];
    atomicAdd(&psum[t], tot);
    const unsigned int c = scnt[t];
    if (c) atomicAdd(&cnt[t], c);       // most experts untouched per block
  }
}

__global__ void aux_finalize(const float* __restrict__ psum,
                             const unsigned int* __restrict__ cnt,
                             float* __restrict__ out) {
  const int t = threadIdx.x;  // 64 threads
  const float f = (float)cnt[t] / (float)(B_ROWS * 2);
  const float P = psum[t] / (float)B_ROWS;
  float v = f * P;
  v = wave_sum64(v);
  if (t == 0) out[4 * B_ROWS] = (float)E_EXP * v;
}

extern "C" void kernel_launch(void* const* d_in, const int* in_sizes, int n_in,
                              void* d_out, int out_size, void* d_ws, size_t ws_size,
                              hipStream_t stream) {
  const float* rf = (const float*)d_in[0];
  const float* gw = (const float*)d_in[1];
  float* out  = (float*)d_out;
  float* psum = (float*)d_ws;
  unsigned int* cnt = (unsigned int*)((char*)d_ws + 256);

  hipMemsetAsync(d_ws, 0, 512, stream);
  router_stream<<<B_ROWS / RPB, NTHR, 0, stream>>>(rf, gw, out, psum, cnt);
  aux_finalize<<<1, 64, 0, stream>>>(psum, cnt, out);
}

// Round 5
// 359.377 us; speedup vs baseline: 1.0089x; 1.0089x over previous
//
#include <hip/hip_runtime.h>
#include <math.h>

// TopKRouter: logits = rf @ gw^T, softmax, top-2, aux load-balance loss.
// rf: [16384, 4096] f32, gw: [64, 4096] f32.
// out (f32 flat): weights [0,32768) | indices-as-float [32768,65536) | aux [65536]
//
// R4: R3 streaming structure (lane = d-slot, block = 8 rows x 64 experts,
// wave = 8 experts, register double-buffer, no barriers in hot loop) with the
// register budget FIXED: __launch_bounds__(512, 1) -> 256-VGPR cap, ~210 used,
// no scratch spill (R3 spilled ~180 MB because arg2=2 acted as min-blocks/CU
// -> 128-VGPR cap). ws: [0,256) psum f32[64] | [256,512) cnt u32[64].

constexpr int B_ROWS = 16384;
constexpr int D_DIM  = 4096;
constexpr int E_EXP  = 64;
constexpr int RPB    = 8;     // rows per block
constexpr int NTHR   = 512;   // 8 waves

__device__ __forceinline__ float wave_max64(float v) {
#pragma unroll
  for (int m = 32; m >= 1; m >>= 1) v = fmaxf(v, __shfl_xor(v, m, 64));
  return v;
}

__device__ __forceinline__ float wave_sum64(float v) {
#pragma unroll
  for (int m = 32; m >= 1; m >>= 1) v += __shfl_xor(v, m, 64);
  return v;
}

// argmax over 64 lanes; ties -> smaller index (matches jax.lax.top_k)
__device__ __forceinline__ void wave_argmax64(float v, int i, float& mv, int& mi) {
#pragma unroll
  for (int m = 32; m >= 1; m >>= 1) {
    float ov = __shfl_xor(v, m, 64);
    int   oi = __shfl_xor(i, m, 64);
    if (ov > v || (ov == v && oi < i)) { v = ov; i = oi; }
  }
  mv = v; mi = i;
}

__global__ __launch_bounds__(NTHR, 1) void router_stream(
    const float* __restrict__ rf, const float* __restrict__ gw,
    float* __restrict__ out, float* __restrict__ psum,
    unsigned int* __restrict__ cnt) {
  __shared__ float lt[RPB][E_EXP + 1];   // final logits tile (+1 pad)
  __shared__ float sP[RPB][E_EXP];
  __shared__ unsigned int scnt[E_EXP];

  const int t    = threadIdx.x;
  const int wv   = t >> 6;               // wave = expert group
  const int lane = t & 63;               // lane = d-slot (4 floats)
  const int row0 = blockIdx.x * RPB;
  const int e0   = wv * 8;

  if (t < E_EXP) scnt[t] = 0;

  const float* ab = rf + (size_t)row0 * D_DIM + 4 * lane;
  const float* wb = gw + (size_t)e0 * D_DIM + 4 * lane;

  float acc[RPB][8];
#pragma unroll
  for (int i = 0; i < RPB; ++i)
#pragma unroll
    for (int j = 0; j < 8; ++j) acc[i][j] = 0.f;

  float4 aA[8], wA[8], aB[8], wB[8];

  auto LDA = [&](float4* dst, const int d) {
#pragma unroll
    for (int i = 0; i < 8; ++i)
      dst[i] = *(const float4*)(ab + (size_t)i * D_DIM + d);
  };
  auto LDW = [&](float4* dst, const int d) {
#pragma unroll
    for (int i = 0; i < 8; ++i)
      dst[i] = *(const float4*)(wb + (size_t)i * D_DIM + d);
  };
  auto FMA = [&](const float4* a, const float4* w) {
#pragma unroll
    for (int i = 0; i < RPB; ++i)
#pragma unroll
      for (int j = 0; j < 8; ++j) {
        acc[i][j] = fmaf(a[i].x, w[j].x, acc[i][j]);
        acc[i][j] = fmaf(a[i].y, w[j].y, acc[i][j]);
        acc[i][j] = fmaf(a[i].z, w[j].z, acc[i][j]);
        acc[i][j] = fmaf(a[i].w, w[j].w, acc[i][j]);
      }
  };

  // 16 k-steps of 256 floats each; 2-deep register pipeline (A/B), no barriers.
  LDA(aA, 0); LDW(wA, 0);
  for (int s = 0; s < 8; ++s) {
    const int d1 = (2 * s + 1) * 256;
    LDA(aB, d1); LDW(wB, d1);
    FMA(aA, wA);
    if (s < 7) {
      const int d2 = (2 * s + 2) * 256;
      LDA(aA, d2); LDW(wA, d2);
    }
    FMA(aB, wB);
  }

  // reduce each acc over the 64 d-slot lanes (butterfly; all lanes get sum)
#pragma unroll
  for (int i = 0; i < RPB; ++i)
#pragma unroll
    for (int j = 0; j < 8; ++j) acc[i][j] = wave_sum64(acc[i][j]);

  if (lane == 0) {
#pragma unroll
    for (int i = 0; i < RPB; ++i)
#pragma unroll
      for (int j = 0; j < 8; ++j) lt[i][e0 + j] = acc[i][j];
  }
  __syncthreads();

  // epilogue: wave wv handles row wv; lane = expert index
  {
    const int r = wv;
    const float lg = lt[r][lane];
    const float m  = wave_max64(lg);
    const float p  = __expf(lg - m);
    const float ss = wave_sum64(p);
    sP[r][lane] = p / ss;

    float v1; int i1;
    wave_argmax64(lg, lane, v1, i1);
    const float lm = (lane == i1) ? -INFINITY : lg;
    float v2; int i2;
    wave_argmax64(lm, lane, v2, i2);
    if (lane == 0) {
      const float ex = expf(v2 - v1);    // v2 <= v1, stable
      const float w1 = 1.f / (1.f + ex);
      const float w2 = ex / (1.f + ex);
      const int row = row0 + r;
      out[row * 2 + 0] = w1;
      out[row * 2 + 1] = w2;
      out[2 * B_ROWS + row * 2 + 0] = (float)i1;
      out[2 * B_ROWS + row * 2 + 1] = (float)i2;
      atomicAdd(&scnt[i1], 1u);
      atomicAdd(&scnt[i2], 1u);
    }
  }
  __syncthreads();

  if (t < E_EXP) {
    float tot = 0.f;
#pragma unroll
    for (int r = 0; r < RPB; ++r) tot += sP[r][t];
    atomicAdd(&psum[t], tot);
    const unsigned int c = scnt[t];
    if (c) atomicAdd(&cnt[t], c);       // most experts untouched per block
  }
}

__global__ void aux_finalize(const float* __restrict__ psum,
                             const unsigned int* __restrict__ cnt,
                             float* __restrict__ out) {
  const int t = threadIdx.x;  // 64 threads
  const float f = (float)cnt[t] / (float)(B_ROWS * 2);
  const float P = psum[t] / (float)B_ROWS;
  float v = f * P;
  v = wave_sum64(v);
  if (t == 0) out[4 * B_ROWS] = (float)E_EXP * v;
}

extern "C" void kernel_launch(void* const* d_in, const int* in_sizes, int n_in,
                              void* d_out, int out_size, void* d_ws, size_t ws_size,
                              hipStream_t stream) {
  const float* rf = (const float*)d_in[0];
  const float* gw = (const float*)d_in[1];
  float* out  = (float*)d_out;
  float* psum = (float*)d_ws;
  unsigned int* cnt = (unsigned int*)((char*)d_ws + 256);

  hipMemsetAsync(d_ws, 0, 512, stream);
  router_stream<<<B_ROWS / RPB, NTHR, 0, stream>>>(rf, gw, out, psum, cnt);
  aux_finalize<<<1, 64, 0, stream>>>(psum, cnt, out);
}

// Round 6
// 348.580 us; speedup vs baseline: 1.0401x; 1.0310x over previous
//
#include <hip/hip_runtime.h>
#include <math.h>

// TopKRouter: logits = rf @ gw^T, softmax, top-2, aux load-balance loss.
// rf: [16384, 4096] f32, gw: [64, 4096] f32.
// out (f32 flat): weights [0,32768) | indices-as-float [32768,65536) | aux [65536]
//
// R5: R4 streaming structure (lane = d-slot, block = 8 rows x 64 experts,
// wave = 8 experts, 2-deep register pipeline, no barriers in hot loop) with
// the register budget forced via amdgpu_waves_per_eu(2,2) -> 256-VGPR cap.
// R3/R4 evidence: __launch_bounds__(512,{1,2}) both left the allocator at a
// 128-VGPR / 4-waves-per-SIMD target -> ~80 regs/thread spilled (WRITE_SIZE
// 180 MB of scratch). Demand is ~210 regs; waves_per_eu is the direct knob.
// ws: [0,256) psum f32[64] | [256,512) cnt u32[64].

constexpr int B_ROWS = 16384;
constexpr int D_DIM  = 4096;
constexpr int E_EXP  = 64;
constexpr int RPB    = 8;     // rows per block
constexpr int NTHR   = 512;   // 8 waves

__device__ __forceinline__ float wave_max64(float v) {
#pragma unroll
  for (int m = 32; m >= 1; m >>= 1) v = fmaxf(v, __shfl_xor(v, m, 64));
  return v;
}

__device__ __forceinline__ float wave_sum64(float v) {
#pragma unroll
  for (int m = 32; m >= 1; m >>= 1) v += __shfl_xor(v, m, 64);
  return v;
}

// argmax over 64 lanes; ties -> smaller index (matches jax.lax.top_k)
__device__ __forceinline__ void wave_argmax64(float v, int i, float& mv, int& mi) {
#pragma unroll
  for (int m = 32; m >= 1; m >>= 1) {
    float ov = __shfl_xor(v, m, 64);
    int   oi = __shfl_xor(i, m, 64);
    if (ov > v || (ov == v && oi < i)) { v = ov; i = oi; }
  }
  mv = v; mi = i;
}

__global__
__attribute__((amdgpu_flat_work_group_size(NTHR, NTHR), amdgpu_waves_per_eu(2, 2)))
void router_stream(
    const float* __restrict__ rf, const float* __restrict__ gw,
    float* __restrict__ out, float* __restrict__ psum,
    unsigned int* __restrict__ cnt) {
  __shared__ float lt[RPB][E_EXP + 1];   // final logits tile (+1 pad)
  __shared__ float sP[RPB][E_EXP];
  __shared__ unsigned int scnt[E_EXP];

  const int t    = threadIdx.x;
  const int wv   = t >> 6;               // wave = expert group
  const int lane = t & 63;               // lane = d-slot (4 floats)
  const int row0 = blockIdx.x * RPB;
  const int e0   = wv * 8;

  if (t < E_EXP) scnt[t] = 0;

  const float* ab = rf + (size_t)row0 * D_DIM + 4 * lane;
  const float* wb = gw + (size_t)e0 * D_DIM + 4 * lane;

  float acc[RPB][8];
#pragma unroll
  for (int i = 0; i < RPB; ++i)
#pragma unroll
    for (int j = 0; j < 8; ++j) acc[i][j] = 0.f;

  float4 aA[8], wA[8], aB[8], wB[8];

  auto LDA = [&](float4* dst, const int d) {
#pragma unroll
    for (int i = 0; i < 8; ++i)
      dst[i] = *(const float4*)(ab + (size_t)i * D_DIM + d);
  };
  auto LDW = [&](float4* dst, const int d) {
#pragma unroll
    for (int i = 0; i < 8; ++i)
      dst[i] = *(const float4*)(wb + (size_t)i * D_DIM + d);
  };
  auto FMA = [&](const float4* a, const float4* w) {
#pragma unroll
    for (int i = 0; i < RPB; ++i)
#pragma unroll
      for (int j = 0; j < 8; ++j) {
        acc[i][j] = fmaf(a[i].x, w[j].x, acc[i][j]);
        acc[i][j] = fmaf(a[i].y, w[j].y, acc[i][j]);
        acc[i][j] = fmaf(a[i].z, w[j].z, acc[i][j]);
        acc[i][j] = fmaf(a[i].w, w[j].w, acc[i][j]);
      }
  };

  // 16 k-steps of 256 floats each; 2-deep register pipeline (A/B), no barriers.
  LDA(aA, 0); LDW(wA, 0);
  for (int s = 0; s < 8; ++s) {
    const int d1 = (2 * s + 1) * 256;
    LDA(aB, d1); LDW(wB, d1);
    FMA(aA, wA);
    if (s < 7) {
      const int d2 = (2 * s + 2) * 256;
      LDA(aA, d2); LDW(wA, d2);
    }
    FMA(aB, wB);
  }

  // reduce each acc over the 64 d-slot lanes (butterfly; all lanes get sum)
#pragma unroll
  for (int i = 0; i < RPB; ++i)
#pragma unroll
    for (int j = 0; j < 8; ++j) acc[i][j] = wave_sum64(acc[i][j]);

  if (lane == 0) {
#pragma unroll
    for (int i = 0; i < RPB; ++i)
#pragma unroll
      for (int j = 0; j < 8; ++j) lt[i][e0 + j] = acc[i][j];
  }
  __syncthreads();

  // epilogue: wave wv handles row wv; lane = expert index
  {
    const int r = wv;
    const float lg = lt[r][lane];
    const float m  = wave_max64(lg);
    const float p  = __expf(lg - m);
    const float ss = wave_sum64(p);
    sP[r][lane] = p / ss;

    float v1; int i1;
    wave_argmax64(lg, lane, v1, i1);
    const float lm = (lane == i1) ? -INFINITY : lg;
    float v2; int i2;
    wave_argmax64(lm, lane, v2, i2);
    if (lane == 0) {
      const float ex = expf(v2 - v1);    // v2 <= v1, stable
      const float w1 = 1.f / (1.f + ex);
      const float w2 = ex / (1.f + ex);
      const int row = row0 + r;
      out[row * 2 + 0] = w1;
      out[row * 2 + 1] = w2;
      out[2 * B_ROWS + row * 2 + 0] = (float)i1;
      out[2 * B_ROWS + row * 2 + 1] = (float)i2;
      atomicAdd(&scnt[i1], 1u);
      atomicAdd(&scnt[i2], 1u);
    }
  }
  __syncthreads();

  if (t < E_EXP) {
    float tot = 0.f;
#pragma unroll
    for (int r = 0; r < RPB; ++r) tot += sP[r][t];
    atomicAdd(&psum[t], tot);
    const unsigned int c = scnt[t];
    if (c) atomicAdd(&cnt[t], c);       // most experts untouched per block
  }
}

__global__ void aux_finalize(const float* __restrict__ psum,
                             const unsigned int* __restrict__ cnt,
                             float* __restrict__ out) {
  const int t = threadIdx.x;  // 64 threads
  const float f = (float)cnt[t] / (float)(B_ROWS * 2);
  const float P = psum[t] / (float)B_ROWS;
  float v = f * P;
  v = wave_sum64(v);
  if (t == 0) out[4 * B_ROWS] = (float)E_EXP * v;
}

extern "C" void kernel_launch(void* const* d_in, const int* in_sizes, int n_in,
                              void* d_out, int out_size, void* d_ws, size_t ws_size,
                              hipStream_t stream) {
  const float* rf = (const float*)d_in[0];
  const float* gw = (const float*)d_in[1];
  float* out  = (float*)d_out;
  float* psum = (float*)d_ws;
  unsigned int* cnt = (unsigned int*)((char*)d_ws + 256);

  hipMemsetAsync(d_ws, 0, 512, stream);
  router_stream<<<B_ROWS / RPB, NTHR, 0, stream>>>(rf, gw, out, psum, cnt);
  aux_finalize<<<1, 64, 0, stream>>>(psum, cnt, out);
}

// Round 7
// 296.670 us; speedup vs baseline: 1.2221x; 1.1750x over previous
//
#include <hip/hip_runtime.h>
#include <math.h>

// TopKRouter: logits = rf @ gw^T, softmax, top-2, aux load-balance loss.
// rf: [16384, 4096] f32, gw: [64, 4096] f32.
// out (f32 flat): weights [0,32768) | indices-as-float [32768,65536) | aux [65536]
//
// R6: fit the streaming kernel in the 128-VGPR budget the allocator insists on
// (R3/R4/R5: launch_bounds and waves_per_eu all left VGPR=128 + ~200 MB scratch
// spill). Tile: chunk = float2/lane (128 d/chunk), a double-buffered (32 regs),
// w single-buffered (16), acc 64, addr ~12 -> ~120 regs, no spill, and 128-VGPR
// occupancy gives 2 blocks/CU = 4 waves/SIMD of TLP to hide the w-L2 latency.
// Reduction: halving-exchange (252 instr vs 768 butterfly); lane l ends with
// row l>>3, expert-in-wave l&7.
// ws: [0,256) psum f32[64] | [256,512) cnt u32[64].

constexpr int B_ROWS = 16384;
constexpr int D_DIM  = 4096;
constexpr int E_EXP  = 64;
constexpr int RPB    = 8;     // rows per block
constexpr int NTHR   = 512;   // 8 waves; wave = 8 experts
constexpr int NCH    = 32;    // chunks: 128 floats of d each

__device__ __forceinline__ float wave_max64(float v) {
#pragma unroll
  for (int m = 32; m >= 1; m >>= 1) v = fmaxf(v, __shfl_xor(v, m, 64));
  return v;
}

__device__ __forceinline__ float wave_sum64(float v) {
#pragma unroll
  for (int m = 32; m >= 1; m >>= 1) v += __shfl_xor(v, m, 64);
  return v;
}

// argmax over 64 lanes; ties -> smaller index (matches jax.lax.top_k)
__device__ __forceinline__ void wave_argmax64(float v, int i, float& mv, int& mi) {
#pragma unroll
  for (int m = 32; m >= 1; m >>= 1) {
    float ov = __shfl_xor(v, m, 64);
    int   oi = __shfl_xor(i, m, 64);
    if (ov > v || (ov == v && oi < i)) { v = ov; i = oi; }
  }
  mv = v; mi = i;
}

__global__ __launch_bounds__(NTHR) void router_stream(
    const float* __restrict__ rf, const float* __restrict__ gw,
    float* __restrict__ out, float* __restrict__ psum,
    unsigned int* __restrict__ cnt) {
  __shared__ float lt[RPB][E_EXP + 1];   // final logits tile (+1 pad)
  __shared__ float sP[RPB][E_EXP];
  __shared__ unsigned int scnt[E_EXP];

  const int t    = threadIdx.x;
  const int wv   = t >> 6;               // wave = expert group
  const int lane = t & 63;               // lane = d-slot (2 floats)
  const int row0 = blockIdx.x * RPB;
  const int e0   = wv * 8;

  if (t < E_EXP) scnt[t] = 0;

  const float* ab = rf + (size_t)row0 * D_DIM + 2 * lane;
  const float* wb = gw + (size_t)e0 * D_DIM + 2 * lane;

  float acc[RPB * 8];                    // acc[i*8+j], i=row, j=expert-in-wave
#pragma unroll
  for (int v = 0; v < RPB * 8; ++v) acc[v] = 0.f;

  float2 aA[8], aB[8], wbuf[8];

  auto LDA = [&](float2* dst, const int d) {
#pragma unroll
    for (int i = 0; i < 8; ++i)
      dst[i] = *(const float2*)(ab + (size_t)i * D_DIM + d);
  };
  auto LDW = [&](const int d) {
#pragma unroll
    for (int j = 0; j < 8; ++j)
      wbuf[j] = *(const float2*)(wb + (size_t)j * D_DIM + d);
  };
  auto FMA = [&](const float2* a) {
#pragma unroll
    for (int j = 0; j < 8; ++j)          // expert-major: frees wbuf[j] early
#pragma unroll
      for (int i = 0; i < 8; ++i) {
        acc[i * 8 + j] = fmaf(a[i].x, wbuf[j].x, acc[i * 8 + j]);
        acc[i * 8 + j] = fmaf(a[i].y, wbuf[j].y, acc[i * 8 + j]);
      }
  };

  // 32 chunks of 128 d-floats; a 2-deep pipeline, w single-buffered.
  LDA(aA, 0);
  LDW(0);
  for (int n = 0; n < NCH; ++n) {
    const int dnext = (n + 1) * 128;
    if (n & 1) {
      if (n + 1 < NCH) LDA(aA, dnext);
      FMA(aB);
    } else {
      if (n + 1 < NCH) LDA(aB, dnext);
      FMA(aA);
    }
    if (n + 1 < NCH) LDW(dnext);
  }

  // halving-exchange reduction across the 64 d-slot lanes.
  // invariant: after step m, acc[v] (v<m) = sum over 2*(64/m)-lane... net:
  // final acc[0] on lane l = full sum of original acc[l].
#pragma unroll
  for (int m = 32; m >= 1; m >>= 1) {
    const bool hi = (lane & m) != 0;
#pragma unroll
    for (int v = 0; v < m; ++v) {
      const float send = hi ? acc[v] : acc[v + m];
      const float recv = __shfl_xor(send, m, 64);
      const float keep = hi ? acc[v + m] : acc[v];
      acc[v] = keep + recv;
    }
  }
  // lane l holds logit(row l>>3, expert e0 + (l&7))
  lt[lane >> 3][e0 + (lane & 7)] = acc[0];
  __syncthreads();

  // epilogue: wave wv handles row wv; lane = expert index
  {
    const int r = wv;
    const float lg = lt[r][lane];
    const float m  = wave_max64(lg);
    const float p  = __expf(lg - m);
    const float ss = wave_sum64(p);
    sP[r][lane] = p / ss;

    float v1; int i1;
    wave_argmax64(lg, lane, v1, i1);
    const float lm = (lane == i1) ? -INFINITY : lg;
    float v2; int i2;
    wave_argmax64(lm, lane, v2, i2);
    if (lane == 0) {
      const float ex = expf(v2 - v1);    // v2 <= v1, stable
      const float w1 = 1.f / (1.f + ex);
      const float w2 = ex / (1.f + ex);
      const int row = row0 + r;
      out[row * 2 + 0] = w1;
      out[row * 2 + 1] = w2;
      out[2 * B_ROWS + row * 2 + 0] = (float)i1;
      out[2 * B_ROWS + row * 2 + 1] = (float)i2;
      atomicAdd(&scnt[i1], 1u);
      atomicAdd(&scnt[i2], 1u);
    }
  }
  __syncthreads();

  if (t < E_EXP) {
    float tot = 0.f;
#pragma unroll
    for (int r = 0; r < RPB; ++r) tot += sP[r][t];
    atomicAdd(&psum[t], tot);
    const unsigned int c = scnt[t];
    if (c) atomicAdd(&cnt[t], c);        // most experts untouched per block
  }
}

__global__ void aux_finalize(const float* __restrict__ psum,
                             const unsigned int* __restrict__ cnt,
                             float* __restrict__ out) {
  const int t = threadIdx.x;  // 64 threads
  const float f = (float)cnt[t] / (float)(B_ROWS * 2);
  const float P = psum[t] / (float)B_ROWS;
  float v = f * P;
  v = wave_sum64(v);
  if (t == 0) out[4 * B_ROWS] = (float)E_EXP * v;
}

extern "C" void kernel_launch(void* const* d_in, const int* in_sizes, int n_in,
                              void* d_out, int out_size, void* d_ws, size_t ws_size,
                              hipStream_t stream) {
  const float* rf = (const float*)d_in[0];
  const float* gw = (const float*)d_in[1];
  float* out  = (float*)d_out;
  float* psum = (float*)d_ws;
  unsigned int* cnt = (unsigned int*)((char*)d_ws + 256);

  hipMemsetAsync(d_ws, 0, 512, stream);
  router_stream<<<B_ROWS / RPB, NTHR, 0, stream>>>(rf, gw, out, psum, cnt);
  aux_finalize<<<1, 64, 0, stream>>>(psum, cnt, out);
}

// Round 8
// 262.696 us; speedup vs baseline: 1.3802x; 1.1293x over previous
//
#include <hip/hip_runtime.h>
#include <math.h>

// TopKRouter: logits = rf @ gw^T, softmax, top-2, aux load-balance loss.
// rf: [16384, 4096] f32, gw: [64, 4096] f32.
// out (f32 flat): weights [0,32768) | indices-as-float [32768,65536) | aux [65536]
//
// R7: bf16-split MFMA GEMM (hi+lo trunc split, 4 terms -> logit err ~2e-5),
// fused softmax/top-2/aux epilogue, near-tie rows (gap < 1e-3) flagged and
// recomputed exactly in fp64 by a cleanup kernel. A staged fp32 via
// global_load_lds into a 4-slot LDS ring (source-swizzled, counted vmcnt,
// raw s_barrier); W pre-split to ws in B-fragment order (L2-hot).
// ws: [0,256) psum | [256,512) cnt | [512,516) flagcnt | [768,+32K) flaglist
//     | [65536, +1MB) W frag stream.

typedef __attribute__((ext_vector_type(8))) short bf16x8;
typedef __attribute__((ext_vector_type(4))) float f32x4;

constexpr int B_ROWS  = 16384;
constexpr int D_DIM   = 4096;
constexpr int E_EXP   = 64;
constexpr int BM      = 64;     // rows per block
constexpr int NTHR    = 512;    // 8 waves: wr = wv>>2 (2 row groups), wc = wv&3 (4 expert groups)
constexpr int KSTEPS  = D_DIM / 32;  // 128
constexpr int FLAGCAP = 8192;
constexpr float GAPTHR = 1e-3f;

__device__ __forceinline__ float wave_max64(float v) {
#pragma unroll
  for (int m = 32; m >= 1; m >>= 1) v = fmaxf(v, __shfl_xor(v, m, 64));
  return v;
}
__device__ __forceinline__ float wave_sum64(float v) {
#pragma unroll
  for (int m = 32; m >= 1; m >>= 1) v += __shfl_xor(v, m, 64);
  return v;
}
// argmax over 64 lanes; ties -> smaller index (matches jax.lax.top_k)
__device__ __forceinline__ void wave_argmax64(float v, int i, float& mv, int& mi) {
#pragma unroll
  for (int m = 32; m >= 1; m >>= 1) {
    float ov = __shfl_xor(v, m, 64);
    int   oi = __shfl_xor(i, m, 64);
    if (ov > v || (ov == v && oi < i)) { v = ov; i = oi; }
  }
  mv = v; mi = i;
}

__device__ __forceinline__ void async_copy16(void* lds_dst, const void* g_src) {
  auto g = (const __attribute__((address_space(1))) char*)(g_src);
  auto l = (__attribute__((address_space(3))) char*)(lds_dst);
  __builtin_amdgcn_global_load_lds(g, l, 16, 0, 0);
}

// trunc-split 8 fp32 -> hi/lo bf16 frags (exact: f = hi + rem; |err| <= 2^-16 |f|)
__device__ __forceinline__ void split8(const f32x4 a, const f32x4 b, bf16x8& hi, bf16x8& lo) {
  float f[8] = {a[0], a[1], a[2], a[3], b[0], b[1], b[2], b[3]};
#pragma unroll
  for (int i = 0; i < 8; ++i) {
    unsigned int u = __float_as_uint(f[i]);
    hi[i] = (short)(u >> 16);
    float rem = f[i] - __uint_as_float(u & 0xffff0000u);
    lo[i] = (short)(__float_as_uint(rem) >> 16);
  }
}

// W pre-split: gw [64][4096] f32 -> ws frag stream [n=k/32][wc][h(hi/lo)][lane][16B].
// B-frag layout for mfma_f32_16x16x32_bf16: lane l elem i <-> B[k=(l>>4)*8+i][col=l&15].
__global__ __launch_bounds__(NTHR) void wsplit(const float* __restrict__ gw,
                                               char* __restrict__ wsW) {
  const int n = blockIdx.x;          // 128 k-steps
  const int t = threadIdx.x;
  const int lane = t & 63, h = (t >> 6) & 1, wc = t >> 7;
  const int col = wc * 16 + (lane & 15);
  const int k0  = n * 32 + (lane >> 4) * 8;
  const float* src = gw + (size_t)col * D_DIM + k0;
  union { unsigned short us[8]; uint4 v; } pk;
#pragma unroll
  for (int i = 0; i < 8; ++i) {
    float f = src[i];
    unsigned int u = __float_as_uint(f);
    if (h == 0) {
      pk.us[i] = (unsigned short)(u >> 16);
    } else {
      float rem = f - __uint_as_float(u & 0xffff0000u);
      pk.us[i] = (unsigned short)(__float_as_uint(rem) >> 16);
    }
  }
  *(uint4*)(wsW + (size_t)n * 8192 + (size_t)t * 16) = pk.v;
}

__global__ __launch_bounds__(NTHR) void gemm_router(
    const float* __restrict__ rf, const char* __restrict__ wsW,
    float* __restrict__ out, float* __restrict__ psum,
    unsigned int* __restrict__ cnt, int* __restrict__ flagcnt,
    int* __restrict__ flaglist) {
  // strip: [A fp32 64x32 (8KB, source-swizzled) | W bf16 frags (8KB)] x 4 slots
  __shared__ char strips[4][16384] __attribute__((aligned(16)));
  __shared__ float lt[BM][E_EXP + 1];
  __shared__ float sPw[8][64];
  __shared__ unsigned int scnt[E_EXP];

  const int t = threadIdx.x, lane = t & 63, wv = t >> 6;
  const int wr = wv >> 2, wc = wv & 3;
  const int row0 = blockIdx.x * BM;
  if (t < E_EXP) scnt[t] = 0;

  // staging map: thread t stages row rA, 16B-slot sA (global col pre-swizzled so
  // linear LDS + swizzled ds_read are conflict-free)
  const int rA = t >> 3, sA = t & 7;
  const char* pA = (const char*)rf +
      ((size_t)(row0 + rA) * D_DIM + (size_t)((sA ^ (rA & 7)) << 2)) * 4;
  const char* pW = wsW + (size_t)t * 16;

  // compute-side A addressing: rows r0f(+16), k-slots s0,s0^1 (XOR bank swizzle)
  const int r0f = wr * 32 + (lane & 15);
  const int x   = lane & 7;
  const int s0  = (lane >> 4) * 2;
  const int sl0 = ((s0 ^ x) << 4), sl1 = (((s0 ^ x) ^ 1) << 4);

  f32x4 acc0 = {0.f, 0.f, 0.f, 0.f}, acc1 = {0.f, 0.f, 0.f, 0.f};

#define ISSUE(n)                                                            \
  {                                                                         \
    char* s_ = strips[(n) & 3];                                             \
    async_copy16(s_ + t * 16, pA + (size_t)(n) * 128);                      \
    async_copy16(s_ + 8192 + t * 16, pW + (size_t)(n) * 8192);              \
  }

#define KSTEP(n, VMSTR, DOISS)                                              \
  {                                                                         \
    asm volatile("s_waitcnt vmcnt(" VMSTR ")" ::: "memory");                \
    __builtin_amdgcn_s_barrier();                                           \
    if (DOISS) ISSUE((n) + 3);                                              \
    const char* sb = strips[(n) & 3];                                       \
    const bf16x8 whi = *(const bf16x8*)(sb + 8192 + wc * 2048 + lane * 16); \
    const bf16x8 wlo = *(const bf16x8*)(sb + 8192 + wc * 2048 + 1024 + lane * 16); \
    {                                                                       \
      const char* ab = sb + r0f * 128;                                      \
      f32x4 fl = *(const f32x4*)(ab + sl0);                                 \
      f32x4 fh = *(const f32x4*)(ab + sl1);                                 \
      bf16x8 ahi, alo;                                                      \
      split8(fl, fh, ahi, alo);                                             \
      acc0 = __builtin_amdgcn_mfma_f32_16x16x32_bf16(ahi, whi, acc0, 0, 0, 0); \
      acc0 = __builtin_amdgcn_mfma_f32_16x16x32_bf16(ahi, wlo, acc0, 0, 0, 0); \
      acc0 = __builtin_amdgcn_mfma_f32_16x16x32_bf16(alo, whi, acc0, 0, 0, 0); \
      acc0 = __builtin_amdgcn_mfma_f32_16x16x32_bf16(alo, wlo, acc0, 0, 0, 0); \
    }                                                                       \
    {                                                                       \
      const char* ab = sb + (r0f + 16) * 128;                               \
      f32x4 fl = *(const f32x4*)(ab + sl0);                                 \
      f32x4 fh = *(const f32x4*)(ab + sl1);                                 \
      bf16x8 ahi, alo;                                                      \
      split8(fl, fh, ahi, alo);                                             \
      acc1 = __builtin_amdgcn_mfma_f32_16x16x32_bf16(ahi, whi, acc1, 0, 0, 0); \
      acc1 = __builtin_amdgcn_mfma_f32_16x16x32_bf16(ahi, wlo, acc1, 0, 0, 0); \
      acc1 = __builtin_amdgcn_mfma_f32_16x16x32_bf16(alo, whi, acc1, 0, 0, 0); \
      acc1 = __builtin_amdgcn_mfma_f32_16x16x32_bf16(alo, wlo, acc1, 0, 0, 0); \
    }                                                                       \
  }

  ISSUE(0); ISSUE(1); ISSUE(2);
  for (int n = 0; n < KSTEPS - 3; ++n) KSTEP(n, "4", 1);
  KSTEP(KSTEPS - 3, "4", 0);
  KSTEP(KSTEPS - 2, "2", 0);
  KSTEP(KSTEPS - 1, "0", 0);
#undef KSTEP
#undef ISSUE

  // scatter logits: D frag -> row = wr*32 + rfid*16 + (lane>>4)*4 + j, col = wc*16 + (lane&15)
  {
    const int cc = wc * 16 + (lane & 15);
    const int rb = wr * 32 + ((lane >> 4) << 2);
#pragma unroll
    for (int j = 0; j < 4; ++j) lt[rb + j][cc] = acc0[j];
#pragma unroll
    for (int j = 0; j < 4; ++j) lt[rb + 16 + j][cc] = acc1[j];
  }
  __syncthreads();

  // epilogue: wave wv handles rows wv*8..+8; lane = expert
  float Pacc = 0.f;
#pragma unroll
  for (int j = 0; j < 8; ++j) {
    const int r = wv * 8 + j;
    const float lg = lt[r][lane];
    const float m  = wave_max64(lg);
    const float p  = __expf(lg - m);
    const float ss = wave_sum64(p);
    Pacc += p / ss;
    float v1; int i1; wave_argmax64(lg, lane, v1, i1);
    const float lm1 = (lane == i1) ? -INFINITY : lg;
    float v2; int i2; wave_argmax64(lm1, lane, v2, i2);
    const float lm2 = (lane == i2) ? -INFINITY : lm1;
    float v3; int i3; wave_argmax64(lm2, lane, v3, i3);
    if (lane == 0) {
      const float ex = expf(v2 - v1);
      const float w1 = 1.f / (1.f + ex);
      const float w2 = ex / (1.f + ex);
      const int row = row0 + r;
      out[row * 2 + 0] = w1;
      out[row * 2 + 1] = w2;
      out[2 * B_ROWS + row * 2 + 0] = (float)i1;
      out[2 * B_ROWS + row * 2 + 1] = (float)i2;
      atomicAdd(&scnt[i1], 1u);
      atomicAdd(&scnt[i2], 1u);
      if (v1 - v2 < GAPTHR || v2 - v3 < GAPTHR) {  // near-tie: exact recompute later
        int fi = atomicAdd(flagcnt, 1);
        if (fi < FLAGCAP) flaglist[fi] = row;
      }
    }
  }
  sPw[wv][lane] = Pacc;
  __syncthreads();
  if (t < E_EXP) {
    float tot = 0.f;
#pragma unroll
    for (int w = 0; w < 8; ++w) tot += sPw[w][t];
    atomicAdd(&psum[t], tot);
    const unsigned int c = scnt[t];
    if (c) atomicAdd(&cnt[t], c);
  }
}

// exact fp64 recompute of flagged (near-tie) rows; overwrites weights+indices.
__global__ __launch_bounds__(256) void cleanup(
    const float* __restrict__ rf, const float* __restrict__ gw,
    const int* __restrict__ flagcnt, const int* __restrict__ flaglist,
    float* __restrict__ out) {
  __shared__ double sm[256];
  const int t = threadIdx.x;
  const int nf = min(*flagcnt, FLAGCAP);
  for (int fi = blockIdx.x; fi < nf; fi += gridDim.x) {
    const int row = flaglist[fi];
    const int e = t & 63, seg = t >> 6;
    const float* a = rf + (size_t)row * D_DIM + seg * 1024;
    const float* w = gw + (size_t)e * D_DIM + seg * 1024;
    double p = 0.0;
    for (int k = 0; k < 1024; ++k) p = fma((double)a[k], (double)w[k], p);
    sm[t] = p;
    __syncthreads();
    if (t < 64) {
      const double l = sm[t] + sm[64 + t] + sm[128 + t] + sm[192 + t];
      double v = l; int ii = t;
#pragma unroll
      for (int m = 32; m >= 1; m >>= 1) {
        double ov = __shfl_xor(v, m, 64); int oi = __shfl_xor(ii, m, 64);
        if (ov > v || (ov == v && oi < ii)) { v = ov; ii = oi; }
      }
      const double v1 = v; const int i1 = ii;
      const double lm = (t == i1) ? -1e300 : l;
      v = lm; ii = t;
#pragma unroll
      for (int m = 32; m >= 1; m >>= 1) {
        double ov = __shfl_xor(v, m, 64); int oi = __shfl_xor(ii, m, 64);
        if (ov > v || (ov == v && oi < ii)) { v = ov; ii = oi; }
      }
      const double v2 = v; const int i2 = ii;
      if (t == 0) {
        const double ex = exp(v2 - v1);
        out[row * 2 + 0] = (float)(1.0 / (1.0 + ex));
        out[row * 2 + 1] = (float)(ex / (1.0 + ex));
        out[2 * B_ROWS + row * 2 + 0] = (float)i1;
        out[2 * B_ROWS + row * 2 + 1] = (float)i2;
      }
    }
    __syncthreads();
  }
}

__global__ void aux_finalize(const float* __restrict__ psum,
                             const unsigned int* __restrict__ cnt,
                             float* __restrict__ out) {
  const int t = threadIdx.x;  // 64 threads
  const float f = (float)cnt[t] / (float)(B_ROWS * 2);
  const float P = psum[t] / (float)B_ROWS;
  float v = f * P;
  v = wave_sum64(v);
  if (t == 0) out[4 * B_ROWS] = (float)E_EXP * v;
}

extern "C" void kernel_launch(void* const* d_in, const int* in_sizes, int n_in,
                              void* d_out, int out_size, void* d_ws, size_t ws_size,
                              hipStream_t stream) {
  const float* rf = (const float*)d_in[0];
  const float* gw = (const float*)d_in[1];
  float* out = (float*)d_out;
  float* psum = (float*)d_ws;
  unsigned int* cnt = (unsigned int*)((char*)d_ws + 256);
  int* flagcnt = (int*)((char*)d_ws + 512);
  int* flaglist = (int*)((char*)d_ws + 768);
  char* wsW = (char*)d_ws + 65536;

  hipMemsetAsync(d_ws, 0, 768, stream);
  wsplit<<<KSTEPS, NTHR, 0, stream>>>(gw, wsW);
  gemm_router<<<B_ROWS / BM, NTHR, 0, stream>>>(rf, wsW, out, psum, cnt,
                                                flagcnt, flaglist);
  cleanup<<<64, 256, 0, stream>>>(rf, gw, flagcnt, flaglist, out);
  aux_finalize<<<1, 64, 0, stream>>>(psum, cnt, out);
}

// Round 9
// 230.513 us; speedup vs baseline: 1.5729x; 1.1396x over previous
//
#include <hip/hip_runtime.h>
#include <math.h>

// TopKRouter: logits = rf @ gw^T, softmax, top-2, aux load-balance loss.
// rf: [16384, 4096] f32, gw: [64, 4096] f32.
// out (f32 flat): weights [0,32768) | indices-as-float [32768,65536) | aux [65536]
//
// R8: barrier-free per-wave pipelines. Block = 16 rows; each of 8 waves owns a
// private 512-wide D-slice (split-D in block) computing 16 rows x 64 experts
// partial via bf16-split MFMA (4 terms). A: global->reg->ds_write into a
// private 2-slot LDS ring (swizzled slots); W: read direct from L2-hot frag
// stream (wsplit). Partials combined via LDS atomics; fused epilogue; near-tie
// rows recomputed fp64 by cleanup.
// ws: [0,256) psum | [256,512) cnt | [512,516) flagcnt | [768,+32K) flaglist
//     | [65536, +1MB) W frag stream.

typedef __attribute__((ext_vector_type(8))) short bf16x8;
typedef __attribute__((ext_vector_type(4))) float f32x4;

constexpr int B_ROWS  = 16384;
constexpr int D_DIM   = 4096;
constexpr int E_EXP   = 64;
constexpr int TM      = 16;     // rows per block
constexpr int NTHR    = 512;    // 8 waves; wave wv owns d-range [wv*512, +512)
constexpr int NS      = 16;     // K-steps per wave, 32 floats each
constexpr int FLAGCAP = 8192;
constexpr float GAPTHR = 1e-3f;

__device__ __forceinline__ float wave_max64(float v) {
#pragma unroll
  for (int m = 32; m >= 1; m >>= 1) v = fmaxf(v, __shfl_xor(v, m, 64));
  return v;
}
__device__ __forceinline__ float wave_sum64(float v) {
#pragma unroll
  for (int m = 32; m >= 1; m >>= 1) v += __shfl_xor(v, m, 64);
  return v;
}
// argmax over 64 lanes; ties -> smaller index (matches jax.lax.top_k)
__device__ __forceinline__ void wave_argmax64(float v, int i, float& mv, int& mi) {
#pragma unroll
  for (int m = 32; m >= 1; m >>= 1) {
    float ov = __shfl_xor(v, m, 64);
    int   oi = __shfl_xor(i, m, 64);
    if (ov > v || (ov == v && oi < i)) { v = ov; i = oi; }
  }
  mv = v; mi = i;
}

// trunc-split 8 fp32 -> hi/lo bf16 frags (f = hi + rem exactly at bf16 precision)
__device__ __forceinline__ void split8(const f32x4 a, const f32x4 b, bf16x8& hi, bf16x8& lo) {
  float f[8] = {a[0], a[1], a[2], a[3], b[0], b[1], b[2], b[3]};
#pragma unroll
  for (int i = 0; i < 8; ++i) {
    unsigned int u = __float_as_uint(f[i]);
    hi[i] = (short)(u >> 16);
    float rem = f[i] - __uint_as_float(u & 0xffff0000u);
    lo[i] = (short)(__float_as_uint(rem) >> 16);
  }
}

// W pre-split: gw [64][4096] f32 -> frag stream [n=k/32][cb][h][lane][16B].
// B-frag (mfma_f32_16x16x32_bf16): lane l elem i <-> B[k=(l>>4)*8+i][col=l&15].
__global__ __launch_bounds__(NTHR) void wsplit(const float* __restrict__ gw,
                                               char* __restrict__ wsW) {
  const int n = blockIdx.x;          // 128 k-steps
  const int t = threadIdx.x;
  const int lane = t & 63, h = (t >> 6) & 1, wc = t >> 7;
  const int col = wc * 16 + (lane & 15);
  const int k0  = n * 32 + (lane >> 4) * 8;
  const float* src = gw + (size_t)col * D_DIM + k0;
  union { unsigned short us[8]; uint4 v; } pk;
#pragma unroll
  for (int i = 0; i < 8; ++i) {
    float f = src[i];
    unsigned int u = __float_as_uint(f);
    if (h == 0) {
      pk.us[i] = (unsigned short)(u >> 16);
    } else {
      float rem = f - __uint_as_float(u & 0xffff0000u);
      pk.us[i] = (unsigned short)(__float_as_uint(rem) >> 16);
    }
  }
  *(uint4*)(wsW + (size_t)n * 8192 + (size_t)t * 16) = pk.v;
}

__global__ __launch_bounds__(NTHR) void gemm_router(
    const float* __restrict__ rf, const char* __restrict__ wsW,
    float* __restrict__ out, float* __restrict__ psum,
    unsigned int* __restrict__ cnt, int* __restrict__ flagcnt,
    int* __restrict__ flaglist) {
  __shared__ char astrip[8][2][2048] __attribute__((aligned(16)));  // per-wave rings
  __shared__ float lt[TM][E_EXP + 2];
  __shared__ float pcol[E_EXP];
  __shared__ unsigned int scnt[E_EXP];

  const int t = threadIdx.x, lane = t & 63, wv = t >> 6;
  const int row0 = blockIdx.x * TM;

  for (int i = t; i < TM * (E_EXP + 2); i += NTHR) ((float*)lt)[i] = 0.f;
  if (t < E_EXP) { scnt[t] = 0; pcol[t] = 0.f; }
  __syncthreads();

  // ---- staging map (global->reg->ds_write, swizzled slots) ----
  // lane stages row rW = lane>>2, global 16B-slots sW, sW+1 of each 128B chunk;
  // LDS slot sigma holds global slot sigma ^ (row&7).
  const int rW = lane >> 2;
  const int sW = (lane & 3) * 2;
  const int xW = rW & 7;
  const float* gsrc = rf + (size_t)(row0 + rW) * D_DIM + wv * (NS * 32) + sW * 4;
  char* mystrip = &astrip[wv][0][0];
  const int wo0 = rW * 128 + (((sW)     ^ xW) << 4);
  const int wo1 = rW * 128 + (((sW + 1) ^ xW) << 4);

  // ---- compute-side A-frag read offsets ----
  const int rr = lane & 15;
  const int s0 = (lane >> 4) * 2;
  const int ro0 = rr * 128 + (((s0) ^ (rr & 7)) << 4);
  const int ro1 = ro0 ^ 16;

  const char* wbase = wsW + (size_t)(wv * NS) * 8192 + (size_t)lane * 16;

  f32x4 acc[4] = {{0.f,0.f,0.f,0.f},{0.f,0.f,0.f,0.f},{0.f,0.f,0.f,0.f},{0.f,0.f,0.f,0.f}};
  f32x4 aR0, aR1;

  auto G = [&](int n) {
    aR0 = *(const f32x4*)(gsrc + n * 32);
    aR1 = *(const f32x4*)(gsrc + n * 32 + 4);
  };
  auto DSW = [&](int slot) {
    char* s = mystrip + slot * 2048;
    *(f32x4*)(s + wo0) = aR0;
    *(f32x4*)(s + wo1) = aR1;
  };

  G(0); DSW(0);
  G(1);
#pragma unroll 2
  for (int n = 0; n < NS; ++n) {
    if (n + 1 < NS) DSW((n + 1) & 1);   // write next step's tile (reg data n+1)
    if (n + 2 < NS) G(n + 2);           // issue global for step n+2
    const char* s = mystrip + (n & 1) * 2048;
    f32x4 fl = *(const f32x4*)(s + ro0);
    f32x4 fh = *(const f32x4*)(s + ro1);
    bf16x8 ahi, alo;
    split8(fl, fh, ahi, alo);
    const char* wn = wbase + (size_t)n * 8192;
#pragma unroll
    for (int cb = 0; cb < 4; ++cb) {
      bf16x8 whi = *(const bf16x8*)(wn + cb * 2048);
      bf16x8 wlo = *(const bf16x8*)(wn + cb * 2048 + 1024);
      acc[cb] = __builtin_amdgcn_mfma_f32_16x16x32_bf16(ahi, whi, acc[cb], 0, 0, 0);
      acc[cb] = __builtin_amdgcn_mfma_f32_16x16x32_bf16(ahi, wlo, acc[cb], 0, 0, 0);
      acc[cb] = __builtin_amdgcn_mfma_f32_16x16x32_bf16(alo, whi, acc[cb], 0, 0, 0);
      acc[cb] = __builtin_amdgcn_mfma_f32_16x16x32_bf16(alo, wlo, acc[cb], 0, 0, 0);
    }
  }

  // combine partials: D frag -> row (lane>>4)*4+j, col cb*16+(lane&15)
  {
    const int colb = lane & 15;
    const int rowb = (lane >> 4) * 4;
#pragma unroll
    for (int cb = 0; cb < 4; ++cb)
#pragma unroll
      for (int j = 0; j < 4; ++j)
        atomicAdd(&lt[rowb + j][cb * 16 + colb], acc[cb][j]);
  }
  __syncthreads();

  // epilogue: wave wv handles rows 2wv, 2wv+1; lane = expert
#pragma unroll
  for (int j = 0; j < 2; ++j) {
    const int r = wv * 2 + j;
    const float lg = lt[r][lane];
    const float m  = wave_max64(lg);
    const float p  = __expf(lg - m);
    const float ss = wave_sum64(p);
    atomicAdd(&pcol[lane], p / ss);
    float v1; int i1; wave_argmax64(lg, lane, v1, i1);
    const float lm1 = (lane == i1) ? -INFINITY : lg;
    float v2; int i2; wave_argmax64(lm1, lane, v2, i2);
    const float lm2 = (lane == i2) ? -INFINITY : lm1;
    float v3; int i3; wave_argmax64(lm2, lane, v3, i3);
    if (lane == 0) {
      const float ex = expf(v2 - v1);
      const int row = row0 + r;
      out[row * 2 + 0] = 1.f / (1.f + ex);
      out[row * 2 + 1] = ex / (1.f + ex);
      out[2 * B_ROWS + row * 2 + 0] = (float)i1;
      out[2 * B_ROWS + row * 2 + 1] = (float)i2;
      atomicAdd(&scnt[i1], 1u);
      atomicAdd(&scnt[i2], 1u);
      if (v1 - v2 < GAPTHR || v2 - v3 < GAPTHR) {
        int fi = atomicAdd(flagcnt, 1);
        if (fi < FLAGCAP) flaglist[fi] = row;
      }
    }
  }
  __syncthreads();
  if (t < E_EXP) {
    atomicAdd(&psum[t], pcol[t]);
    const unsigned int c = scnt[t];
    if (c) atomicAdd(&cnt[t], c);
  }
}

// exact fp64 recompute of flagged (near-tie) rows; overwrites weights+indices.
__global__ __launch_bounds__(256) void cleanup(
    const float* __restrict__ rf, const float* __restrict__ gw,
    const int* __restrict__ flagcnt, const int* __restrict__ flaglist,
    float* __restrict__ out) {
  __shared__ double sm[256];
  const int t = threadIdx.x;
  const int nf = min(*flagcnt, FLAGCAP);
  for (int fi = blockIdx.x; fi < nf; fi += gridDim.x) {
    const int row = flaglist[fi];
    const int e = t & 63, seg = t >> 6;
    const float* a = rf + (size_t)row * D_DIM + seg * 1024;
    const float* w = gw + (size_t)e * D_DIM + seg * 1024;
    double p0 = 0.0, p1 = 0.0, p2 = 0.0, p3 = 0.0;
    for (int k = 0; k < 1024; k += 4) {
      p0 = fma((double)a[k + 0], (double)w[k + 0], p0);
      p1 = fma((double)a[k + 1], (double)w[k + 1], p1);
      p2 = fma((double)a[k + 2], (double)w[k + 2], p2);
      p3 = fma((double)a[k + 3], (double)w[k + 3], p3);
    }
    sm[t] = (p0 + p1) + (p2 + p3);
    __syncthreads();
    if (t < 64) {
      const double l = sm[t] + sm[64 + t] + sm[128 + t] + sm[192 + t];
      double v = l; int ii = t;
#pragma unroll
      for (int m = 32; m >= 1; m >>= 1) {
        double ov = __shfl_xor(v, m, 64); int oi = __shfl_xor(ii, m, 64);
        if (ov > v || (ov == v && oi < ii)) { v = ov; ii = oi; }
      }
      const double v1 = v; const int i1 = ii;
      const double lm = (t == i1) ? -1e300 : l;
      v = lm; ii = t;
#pragma unroll
      for (int m = 32; m >= 1; m >>= 1) {
        double ov = __shfl_xor(v, m, 64); int oi = __shfl_xor(ii, m, 64);
        if (ov > v || (ov == v && oi < ii)) { v = ov; ii = oi; }
      }
      const double v2 = v; const int i2 = ii;
      if (t == 0) {
        const double ex = exp(v2 - v1);
        out[row * 2 + 0] = (float)(1.0 / (1.0 + ex));
        out[row * 2 + 1] = (float)(ex / (1.0 + ex));
        out[2 * B_ROWS + row * 2 + 0] = (float)i1;
        out[2 * B_ROWS + row * 2 + 1] = (float)i2;
      }
    }
    __syncthreads();
  }
}

__global__ void aux_finalize(const float* __restrict__ psum,
                             const unsigned int* __restrict__ cnt,
                             float* __restrict__ out) {
  const int t = threadIdx.x;  // 64 threads
  const float f = (float)cnt[t] / (float)(B_ROWS * 2);
  const float P = psum[t] / (float)B_ROWS;
  float v = f * P;
  v = wave_sum64(v);
  if (t == 0) out[4 * B_ROWS] = (float)E_EXP * v;
}

extern "C" void kernel_launch(void* const* d_in, const int* in_sizes, int n_in,
                              void* d_out, int out_size, void* d_ws, size_t ws_size,
                              hipStream_t stream) {
  const float* rf = (const float*)d_in[0];
  const float* gw = (const float*)d_in[1];
  float* out = (float*)d_out;
  float* psum = (float*)d_ws;
  unsigned int* cnt = (unsigned int*)((char*)d_ws + 256);
  int* flagcnt = (int*)((char*)d_ws + 512);
  int* flaglist = (int*)((char*)d_ws + 768);
  char* wsW = (char*)d_ws + 65536;

  hipMemsetAsync(d_ws, 0, 768, stream);
  wsplit<<<D_DIM / 32, NTHR, 0, stream>>>(gw, wsW);
  gemm_router<<<B_ROWS / TM, NTHR, 0, stream>>>(rf, wsW, out, psum, cnt,
                                                flagcnt, flaglist);
  cleanup<<<64, 256, 0, stream>>>(rf, gw, flagcnt, flaglist, out);
  aux_finalize<<<1, 64, 0, stream>>>(psum, cnt, out);
}